// Round 3
// baseline (113.307 us; speedup 1.0000x reference)
//
#include <hip/hip_runtime.h>
#include <hip/hip_bf16.h>

// Tile-gather: out[b,c,h,w] = (1/64) Σ_n Σ_p wy[h,p] Σ_q wx[w,q] patch[b,n,c,p,q]
// sigma=0.2 -> exp(-12.5 d^2): support radius 2 px, so a brush touches a
// <=20x20 px window. One block per 16x16 output tile; block-uniform brush
// culling (~1.3 of 64 brushes survive per tile); patch staged in LDS;
// coalesced single store per output element (no memset, no atomics).

#define TILE 16

__global__ __launch_bounds__(256) void brush_tile(
        const float* __restrict__ brushes,   // [32,64,2]
        const float* __restrict__ patches,   // [32,64,3,16,16]
        float* __restrict__ out)             // [32,3,256,256]
{
    const int b   = blockIdx.z;
    const int tx  = blockIdx.x * TILE;
    const int ty  = blockIdx.y * TILE;
    const int tid = threadIdx.x;
    const int w   = tx + (tid & 15);
    const int h   = ty + (tid >> 4);

    __shared__ float gxy[128];   // [n][{gx,gy}] in pixels
    __shared__ float sp[768];    // patch [c][p][q] of current brush
    __shared__ float invZ[32];   // [0..15]=x taps, [16..31]=y taps

    if (tid < 128) gxy[tid] = brushes[(b << 7) + tid] * 256.0f;
    __syncthreads();

    float acc0 = 0.0f, acc1 = 0.0f, acc2 = 0.0f;
    const float fw = (float)w, fh = (float)h;
    const float txlo = (float)tx, tylo = (float)ty;

    for (int n = 0; n < 64; ++n) {
        const float gx = gxy[2 * n], gy = gxy[2 * n + 1];
        // window [g-9.5, g+9.5] vs tile [t, t+15] — uniform across the block
        if (gx < txlo - 9.5f || gx > txlo + 24.5f ||
            gy < tylo - 9.5f || gy > tylo + 24.5f) continue;

        __syncthreads();   // previous brush's LDS readers done
        const float* pb = patches + (size_t)((b << 6) + n) * 768;
        sp[tid]       = pb[tid];
        sp[tid + 256] = pb[tid + 256];
        sp[tid + 512] = pb[tid + 512];
        if (tid < 32) {
            const int axis = tid >> 4, q = tid & 15;
            const float g  = axis ? gy : gx;
            const float mu = g + (float)q - 7.5f;
            const float fl = floorf(mu);
            float Z = 0.0f;
#pragma unroll
            for (int d = -1; d <= 2; ++d) {
                const float c = fl + (float)d;
                if (c >= -8.0f && c <= 263.0f) {   // padded coord range
                    const float u = c - mu;
                    Z += __expf(-12.5f * u * u);
                }
            }
            invZ[tid] = 1.0f / (Z + 1e-7f);
        }
        __syncthreads();

        const float ax = fw - gx + 7.5f;
        const float ay = fh - gy + 7.5f;
        if (ax >= -2.0f && ax <= 17.0f && ay >= -2.0f && ay <= 17.0f) {
            int qlo = max(0, (int)ceilf(ax - 2.0f));
            int qhi = min(15, (int)floorf(ax + 2.0f));
            int plo = max(0, (int)ceilf(ay - 2.0f));
            int phi = min(15, (int)floorf(ay + 2.0f));
            const int nq = qhi - qlo + 1;          // <= 5
            float wx[5];
            for (int j = 0; j < nq; ++j) {
                const float d = ax - (float)(qlo + j);
                wx[j] = __expf(-12.5f * d * d) * invZ[qlo + j];
            }
            for (int p = plo; p <= phi; ++p) {
                const float d  = ay - (float)p;
                const float wy = __expf(-12.5f * d * d) * invZ[16 + p];
                const float* row = &sp[(p << 4) + qlo];
                float s0 = 0.0f, s1 = 0.0f, s2 = 0.0f;
                for (int j = 0; j < nq; ++j) {
                    const float t = wx[j];
                    s0 += t * row[j];
                    s1 += t * row[256 + j];
                    s2 += t * row[512 + j];
                }
                acc0 += wy * s0;
                acc1 += wy * s1;
                acc2 += wy * s2;
            }
        }
    }

    const float sc = 1.0f / 64.0f;
    float* ob = out + (((size_t)(b * 3)) << 16) + (h << 8) + w;
    ob[0]       = acc0 * sc;
    ob[1 << 16] = acc1 * sc;
    ob[2 << 16] = acc2 * sc;
}

extern "C" void kernel_launch(void* const* d_in, const int* in_sizes, int n_in,
                              void* d_out, int out_size, void* d_ws, size_t ws_size,
                              hipStream_t stream) {
    const float* brushes = (const float*)d_in[0];
    const float* patches = (const float*)d_in[1];
    float* out = (float*)d_out;
    brush_tile<<<dim3(16, 16, 32), dim3(256), 0, stream>>>(brushes, patches, out);
}

// Round 4
// 89.348 us; speedup vs baseline: 1.2682x; 1.2682x over previous
//
#include <hip/hip_runtime.h>
#include <hip/hip_bf16.h>

// Tile-gather with ballot-compacted brush list.
// out[b,c,h,w] = (1/64) Σ_n Σ_p wy[h,p] Σ_q wx[w,q] patch[b,n,c,p,q]
// sigma=0.2 -> exp(-12.5 d^2): support radius 2 px => brush window <=20x20 px.
// One block per 16x16 tile. Wave 0 ballots the <=64 brushes against the tile
// window (expected ~1.3 survivors); main loop walks set bits only.

#define TILE 16

__global__ __launch_bounds__(256) void brush_tile(
        const float* __restrict__ brushes,   // [32,64,2]
        const float* __restrict__ patches,   // [32,64,3,16,16]
        float* __restrict__ out)             // [32,3,256,256]
{
    const int b   = blockIdx.z;
    const int tx  = blockIdx.x * TILE;
    const int ty  = blockIdx.y * TILE;
    const int tid = threadIdx.x;
    const int w   = tx + (tid & 15);
    const int h   = ty + (tid >> 4);

    __shared__ float gxy[128];               // [n][{gx,gy}] px
    __shared__ unsigned long long smask;     // survivor bitmask
    __shared__ float sp[768];                // patch [c][p][q] of current brush
    __shared__ float invZ[32];               // [0..15]=x, [16..31]=y

    if (tid < 128) gxy[tid] = brushes[(b << 7) + tid] * 256.0f;
    __syncthreads();

    if (tid < 64) {                          // wave 0: lane = brush id
        const float gx = gxy[2 * tid], gy = gxy[2 * tid + 1];
        const bool hit =
            (gx >= (float)tx - 9.5f) & (gx <= (float)tx + 24.5f) &
            (gy >= (float)ty - 9.5f) & (gy <= (float)ty + 24.5f);
        const unsigned long long m = __ballot(hit);
        if (tid == 0) smask = m;
    }
    __syncthreads();
    unsigned long long mask = smask;

    float acc0 = 0.0f, acc1 = 0.0f, acc2 = 0.0f;
    const float fw = (float)w, fh = (float)h;

    while (mask) {
        const int n = __builtin_ctzll(mask);
        mask &= mask - 1;
        const float gx = gxy[2 * n], gy = gxy[2 * n + 1];

        // stage patch (192 lanes, float4) + normalizers (lanes 192..223)
        const float* pb = patches + (size_t)((b << 6) + n) * 768;
        if (tid < 192) {
            ((float4*)sp)[tid] = ((const float4*)pb)[tid];
        } else if (tid < 224) {
            const int t = tid - 192;
            const int axis = t >> 4, q = t & 15;
            const float g  = axis ? gy : gx;
            const float mu = g + (float)q - 7.5f;
            const float fl = floorf(mu);
            float Z = 0.0f;
#pragma unroll
            for (int d = -1; d <= 2; ++d) {
                const float c = fl + (float)d;
                if (c >= -8.0f && c <= 263.0f) {   // padded coord range
                    const float u = c - mu;
                    Z += __expf(-12.5f * u * u);
                }
            }
            invZ[t] = 1.0f / (Z + 1e-7f);
        }
        __syncthreads();

        const float ax = fw - gx + 7.5f;
        const float ay = fh - gy + 7.5f;
        if (ax >= -2.0f && ax <= 17.0f && ay >= -2.0f && ay <= 17.0f) {
            const int qlo = max(0, (int)ceilf(ax - 2.0f));
            const int qhi = min(15, (int)floorf(ax + 2.0f));
            const int plo = max(0, (int)ceilf(ay - 2.0f));
            const int phi = min(15, (int)floorf(ay + 2.0f));
            const int nq = qhi - qlo + 1;          // <= 5
            float wx[5];
            for (int j = 0; j < nq; ++j) {
                const float d = ax - (float)(qlo + j);
                wx[j] = __expf(-12.5f * d * d) * invZ[qlo + j];
            }
            for (int p = plo; p <= phi; ++p) {
                const float d  = ay - (float)p;
                const float wy = __expf(-12.5f * d * d) * invZ[16 + p];
                const float* row = &sp[(p << 4) + qlo];
                float s0 = 0.0f, s1 = 0.0f, s2 = 0.0f;
                for (int j = 0; j < nq; ++j) {
                    const float t = wx[j];
                    s0 += t * row[j];
                    s1 += t * row[256 + j];
                    s2 += t * row[512 + j];
                }
                acc0 += wy * s0;
                acc1 += wy * s1;
                acc2 += wy * s2;
            }
        }
        __syncthreads();   // protect sp/invZ before next staging
    }

    const float sc = 1.0f / 64.0f;
    float* ob = out + (((size_t)(b * 3)) << 16) + (h << 8) + w;
    ob[0]       = acc0 * sc;
    ob[1 << 16] = acc1 * sc;
    ob[2 << 16] = acc2 * sc;
}

extern "C" void kernel_launch(void* const* d_in, const int* in_sizes, int n_in,
                              void* d_out, int out_size, void* d_ws, size_t ws_size,
                              hipStream_t stream) {
    const float* brushes = (const float*)d_in[0];
    const float* patches = (const float*)d_in[1];
    float* out = (float*)d_out;
    brush_tile<<<dim3(16, 16, 32), dim3(256), 0, stream>>>(brushes, patches, out);
}

// Round 5
// 79.402 us; speedup vs baseline: 1.4270x; 1.1253x over previous
//
#include <hip/hip_runtime.h>
#include <hip/hip_bf16.h>

// Two-stage separable tile-gather.
// out[b,c,h,w] = (1/64) Σ_n Σ_p wy[h,p] Σ_q wx[w,q] patch[b,n,c,p,q]
// sigma=0.2 -> exp(-12.5 d^2): support radius ~2 px. One block per 16x16 tile;
// ballot-compacted brush list; per brush:
//   scale : sp4[p][q] = (c-packed patch) * invZx[q]          (float4, b128)
//   stage1: T4[wi][p] = invZy[p] * Σ_q w̃x(wi,q) * sp4[p][q]  (shared by 16 rows)
//   stage2: acc(px)  += Σ_p w̃y(p) * T4[wi][p]
// Gaussians evaluated incrementally: w̃_{j+1} = w̃_j * u, u *= exp(-25)
// (2 exps per axis instead of 5). LDS pads are zeroed so clamped tap windows
// read exact zeros.

#define TILE 16

__global__ __launch_bounds__(256) void brush_tile(
        const float* __restrict__ brushes,   // [32,64,2]
        const float* __restrict__ patches,   // [32,64,3,16,16]
        float* __restrict__ out)             // [32,3,256,256]
{
    const int b   = blockIdx.z;
    const int tx  = blockIdx.x * TILE;
    const int ty  = blockIdx.y * TILE;
    const int tid = threadIdx.x;
    const int w   = tx + (tid & 15);
    const int h   = ty + (tid >> 4);

    __shared__ float  gxy[128];              // [n][{gx,gy}] px
    __shared__ unsigned long long smask;
    __shared__ float4 sp4[16 * 21];          // [p][q(16)+pad], c-packed, *invZx[q]
    __shared__ float4 T4 [16 * 21];          // [wi][p(16)+pad], *invZy[p]
    __shared__ float  invZ[32];              // [0..15]=x, [16..31]=y

    if (tid < 32) {
        float4 v = ((const float4*)(brushes + (b << 7)))[tid];
        v.x *= 256.0f; v.y *= 256.0f; v.z *= 256.0f; v.w *= 256.0f;
        ((float4*)gxy)[tid] = v;
    }
    __syncthreads();

    if (tid < 64) {                          // wave 0: lane = brush id
        const float gx = gxy[2 * tid], gy = gxy[2 * tid + 1];
        const bool hit =
            (gx >= (float)tx - 9.5f) & (gx <= (float)tx + 24.5f) &
            (gy >= (float)ty - 9.5f) & (gy <= (float)ty + 24.5f);
        const unsigned long long m = __ballot(hit);
        if (tid == 0) smask = m;
    }
    __syncthreads();
    unsigned long long mask = smask;

    float acc0 = 0.0f, acc1 = 0.0f, acc2 = 0.0f;
    const float fh = (float)h;
    const float E25 = 1.3887944e-11f;        // exp(-25)

    while (mask) {
        const int n = __builtin_ctzll(mask);
        mask &= mask - 1;
        const float gx = gxy[2 * n], gy = gxy[2 * n + 1];

        // prefetch this brush's patch values (3 coalesced b32 per thread)
        const float* pb = patches + (size_t)((b << 6) + n) * 768;
        const float r0 = pb[tid];
        const float r1 = pb[tid + 256];
        const float r2 = pb[tid + 512];

        // normalizers: lanes 0..31 (safe: invZ not read by prior stage2)
        if (tid < 32) {
            const int axis = tid >> 4, q = tid & 15;
            const float g  = axis ? gy : gx;
            const float mu = g + (float)q - 7.5f;
            const float fl = floorf(mu);
            float Z = 0.0f;
#pragma unroll
            for (int d = -1; d <= 2; ++d) {
                const float c = fl + (float)d;
                if (c >= -8.0f && c <= 263.0f) {   // padded coord range
                    const float u = c - mu;
                    Z += __expf(-12.5f * u * u);
                }
            }
            invZ[tid] = 1.0f / (Z + 1e-7f);
        }
        __syncthreads();                                     // B1

        // scale: stage patch c-packed with invZx baked in
        {
            const int q = tid & 15, p = tid >> 4;
            const float zx = invZ[q];
            sp4[p * 21 + q] = make_float4(r0 * zx, r1 * zx, r2 * zx, 0.0f);
            if (tid < 64)   // zero pads q=16..19
                sp4[(tid >> 2) * 21 + 16 + (tid & 3)] = make_float4(0, 0, 0, 0);
        }
        __syncthreads();                                     // B2

        // stage1: T4[wi][p] = invZy[p] * Σ_q w̃x(wi,q) * sp4[p][q]
        {
            const int wi = tid & 15, p = tid >> 4;
            const float ax = (float)(tx + wi) - gx + 7.5f;
            float4 s = make_float4(0, 0, 0, 0);
            if (ax >= -2.5f && ax <= 17.5f) {
                int qlo = (int)ceilf(ax - 2.0f);
                qlo = qlo < 0 ? 0 : (qlo > 15 ? 15 : qlo);
                const float d0 = ax - (float)qlo;            // in [-2.5, 2.5]
                float wgt = __expf(-12.5f * d0 * d0);
                float u   = __expf(25.0f * d0 - 12.5f);
                const float4* row = &sp4[p * 21 + qlo];
#pragma unroll
                for (int j = 0; j < 5; ++j) {
                    const float4 v = row[j];
                    s.x += wgt * v.x; s.y += wgt * v.y; s.z += wgt * v.z;
                    wgt *= u; u *= E25;
                }
                const float zy = invZ[16 + p];
                s.x *= zy; s.y *= zy; s.z *= zy;
            }
            T4[wi * 21 + p] = s;
            if (tid < 64)   // zero pads p=16..19
                T4[(tid >> 2) * 21 + 16 + (tid & 3)] = make_float4(0, 0, 0, 0);
        }
        __syncthreads();                                     // B3

        // stage2: acc += Σ_p w̃y(p) * T4[wi][p]
        {
            const float ay = fh - gy + 7.5f;
            if (ay >= -2.5f && ay <= 17.5f) {
                int plo = (int)ceilf(ay - 2.0f);
                plo = plo < 0 ? 0 : (plo > 15 ? 15 : plo);
                const float d0 = ay - (float)plo;            // in [-2.5, 2.5]
                float wgt = __expf(-12.5f * d0 * d0);
                float u   = __expf(25.0f * d0 - 12.5f);
                const float4* row = &T4[(tid & 15) * 21 + plo];
#pragma unroll
                for (int j = 0; j < 5; ++j) {
                    const float4 v = row[j];
                    acc0 += wgt * v.x; acc1 += wgt * v.y; acc2 += wgt * v.z;
                    wgt *= u; u *= E25;
                }
            }
        }
        // no trailing barrier: next iteration's B1 separates stage2 reads
        // from the next sp4/T4 writes; invZ is not touched by stage2.
    }

    const float sc = 1.0f / 64.0f;
    float* ob = out + (((size_t)(b * 3)) << 16) + (h << 8) + w;
    ob[0]       = acc0 * sc;
    ob[1 << 16] = acc1 * sc;
    ob[2 << 16] = acc2 * sc;
}

extern "C" void kernel_launch(void* const* d_in, const int* in_sizes, int n_in,
                              void* d_out, int out_size, void* d_ws, size_t ws_size,
                              hipStream_t stream) {
    const float* brushes = (const float*)d_in[0];
    const float* patches = (const float*)d_in[1];
    float* out = (float*)d_out;
    brush_tile<<<dim3(16, 16, 32), dim3(256), 0, stream>>>(brushes, patches, out);
}

// Round 7
// 78.277 us; speedup vs baseline: 1.4475x; 1.0144x over previous
//
#include <hip/hip_runtime.h>
#include <hip/hip_bf16.h>

// Separable tile-gather, shuffle-based stage1 (branchless shuffles).
// out[b,c,h,w] = (1/64) Σ_n Σ_p wy[h,p] Σ_q wx[w,q] patch[b,n,c,p,q]
// sigma=0.2 -> support radius 2 px => brush window <=20x20 px.
// One block per 16x16 tile; wave-0 ballot compacts the brush list (~1.13
// survivors/tile). Per brush (2 barriers):
//   B1: invZ ready. stage1: thread (wi=tid&15, p=tid>>4) forms
//       T4[wi][p] = invZy[p] * Σ_j wx_j * (patch[:,p,qlo+j]*invZx[.])
//       via intra-wave __shfl (patch row p lives in the same wave).
//       CRITICAL: shuffles are executed by ALL lanes (uniform control flow) —
//       ds_bpermute reads from exec-masked-off lanes are undefined, so
//       out-of-range lanes must stay active and mask via weights instead.
//   B2: T4 ready. stage2: pixel (w=tid&15, h=tid>>4) takes 5 p-taps from LDS.
// Incremental Gaussian: w_{j+1}=w_j*u, u*=exp(-25); d0 clamped to [-3,3] so
// the chain stays finite for masked lanes (0*finite==0, no NaN).
// T4 pads p=16..20 zeroed once. WAR on T4 (stage2 reads vs next stage1
// writes) is separated by the next iteration's B1.

#define TILE 16

__global__ __launch_bounds__(256) void brush_tile(
        const float* __restrict__ brushes,   // [32,64,2]
        const float* __restrict__ patches,   // [32,64,3,16,16]
        float* __restrict__ out)             // [32,3,256,256]
{
    const int b   = blockIdx.z;
    const int tx  = blockIdx.x * TILE;
    const int ty  = blockIdx.y * TILE;
    const int tid = threadIdx.x;
    const int qi  = tid & 15;    // q (source) / wi (stage1) / w-col (stage2)
    const int pi  = tid >> 4;    // p (source, stage1) / h-row (stage2)
    const int w   = tx + qi;
    const int h   = ty + pi;

    __shared__ float  gxy[128];              // [n][{gx,gy}] px
    __shared__ unsigned long long smask;
    __shared__ float  invZ[32];              // [0..15]=x, [16..31]=y
    __shared__ float4 T4[16 * 21];           // [wi][p(16)+pad5], c-packed

    // zero T4 pads once (stage1 never writes p>=16)
    if (tid < 80)
        T4[(tid / 5) * 21 + 16 + (tid % 5)] = make_float4(0, 0, 0, 0);

    // wave 0: load + scale coords, ballot vs tile window, stage to LDS
    if (tid < 64) {
        float2 g = ((const float2*)brushes)[(b << 6) + tid];
        g.x *= 256.0f; g.y *= 256.0f;
        ((float2*)gxy)[tid] = g;
        const bool hit =
            (g.x >= (float)tx - 9.5f) & (g.x <= (float)tx + 24.5f) &
            (g.y >= (float)ty - 9.5f) & (g.y <= (float)ty + 24.5f);
        const unsigned long long m = __ballot(hit);
        if (tid == 0) smask = m;
    }
    __syncthreads();                                     // B0
    unsigned long long mask = smask;

    float acc0 = 0.0f, acc1 = 0.0f, acc2 = 0.0f;
    const float E25 = 1.3887944e-11f;                    // exp(-25)

    while (mask) {
        const int n = __builtin_ctzll(mask);
        mask &= mask - 1;
        const float gx = gxy[2 * n], gy = gxy[2 * n + 1];

        // patch loads: 3 coalesced b32, in flight across invZ + B1
        const float* pb = patches + (size_t)((b << 6) + n) * 768;
        const float r0 = pb[tid];
        const float r1 = pb[tid + 256];
        const float r2 = pb[tid + 512];

        if (tid < 32) {                      // normalizers
            const int axis = tid >> 4, q = tid & 15;
            const float g  = axis ? gy : gx;
            const float mu = g + (float)q - 7.5f;
            const float fl = floorf(mu);
            float Z = 0.0f;
#pragma unroll
            for (int d = -1; d <= 2; ++d) {
                const float c = fl + (float)d;
                if (c >= -8.0f && c <= 263.0f) {   // padded coord range
                    const float u = c - mu;
                    Z += __expf(-12.5f * u * u);
                }
            }
            invZ[tid] = 1.0f / (Z + 1e-7f);
        }
        __syncthreads();                                 // B1

        // pre-scale own patch element by invZx[its q]
        const float zx = invZ[qi];
        const float v0 = r0 * zx, v1 = r1 * zx, v2 = r2 * zx;

        // stage1: T4[wi=qi][p=pi] via intra-wave shuffles — BRANCHLESS
        {
            const float ax  = (float)w - gx + 7.5f;
            const bool  okx = (ax >= -2.5f) & (ax <= 17.5f);
            int qlo = (int)ceilf(ax - 2.0f);
            qlo = qlo < 0 ? 0 : (qlo > 15 ? 15 : qlo);
            float d0 = ax - (float)qlo;
            d0 = fminf(fmaxf(d0, -3.0f), 3.0f);          // keep exp chain finite
            float wgt = okx ? __expf(-12.5f * d0 * d0) : 0.0f;
            float u   = __expf(25.0f * d0 - 12.5f);      // <= e^62.5, finite
            const int base = ((pi & 3) << 4) + qlo;      // intra-wave src lane
            float4 s = make_float4(0, 0, 0, 0);
#pragma unroll
            for (int j = 0; j < 5; ++j) {
                const float a0 = __shfl(v0, base + j, 64);  // all lanes active
                const float a1 = __shfl(v1, base + j, 64);
                const float a2 = __shfl(v2, base + j, 64);
                const float wj = (qlo + j < 16) ? wgt : 0.0f;
                s.x += wj * a0; s.y += wj * a1; s.z += wj * a2;
                wgt *= u; u *= E25;
            }
            const float zy = invZ[16 + pi];
            s.x *= zy; s.y *= zy; s.z *= zy;
            T4[qi * 21 + pi] = s;
        }
        __syncthreads();                                 // B2

        // stage2: 5 p-taps from T4 row (pads are exact zeros; LDS reads
        // don't depend on other lanes' exec mask, so divergence is fine)
        {
            const float ay = (float)h - gy + 7.5f;
            if (ay >= -2.5f && ay <= 17.5f) {
                int plo = (int)ceilf(ay - 2.0f);
                plo = plo < 0 ? 0 : (plo > 15 ? 15 : plo);
                const float d0 = ay - (float)plo;        // in [-2.5, 2.5]
                float wgt = __expf(-12.5f * d0 * d0);
                float u   = __expf(25.0f * d0 - 12.5f);
                const float4* row = &T4[qi * 21 + plo];
#pragma unroll
                for (int j = 0; j < 5; ++j) {
                    const float4 v = row[j];
                    acc0 += wgt * v.x; acc1 += wgt * v.y; acc2 += wgt * v.z;
                    wgt *= u; u *= E25;
                }
            }
        }
        // next iteration's B1 separates these T4 reads from the next writes
    }

    const float sc = 1.0f / 64.0f;
    float* ob = out + (((size_t)(b * 3)) << 16) + (h << 8) + w;
    ob[0]       = acc0 * sc;
    ob[1 << 16] = acc1 * sc;
    ob[2 << 16] = acc2 * sc;
}

extern "C" void kernel_launch(void* const* d_in, const int* in_sizes, int n_in,
                              void* d_out, int out_size, void* d_ws, size_t ws_size,
                              hipStream_t stream) {
    const float* brushes = (const float*)d_in[0];
    const float* patches = (const float*)d_in[1];
    float* out = (float*)d_out;
    brush_tile<<<dim3(16, 16, 32), dim3(256), 0, stream>>>(brushes, patches, out);
}